// Round 7
// baseline (256.351 us; speedup 1.0000x reference)
//
#include <hip/hip_runtime.h>
#include <hip/hip_bf16.h>

#define ALPHA 0.2f
constexpr int N = 2048;
constexpr int NW = N / 64;     // 32 mask words per row

typedef __attribute__((ext_vector_type(8))) short short8v;  // bf16 bits x8
typedef __attribute__((ext_vector_type(4))) float f32x4;

__device__ inline unsigned short bf16_rne(float f) {
  unsigned u = __float_as_uint(f);
  return (unsigned short)((u + 0x7fffu + ((u >> 16) & 1u)) >> 16);
}

struct GParams {
  const float* nf; const int* adj;
  const float *encW1, *encb1, *encW2, *encb2;
  const float *gatW0, *gata0, *gatW1, *gata1, *gatW2, *gata2;
  unsigned long long* mask;
  unsigned short *wt0hi, *wt0lo, *wt1hi, *wt1lo;
  unsigned short *x0hi, *x0lo;
  unsigned short* hT;
  float *s1, *s2, *pm1, *pm1h3;
  unsigned short *xAhi, *xAlo;
  float *xB, *h2, *emb;
  unsigned* bar;
};

// ---- device-scope grid barrier (512 co-resident blocks; bar[0]=count, bar[32]=generation) ----
__device__ inline void gsync(unsigned* bar) {
  __syncthreads();
  if (threadIdx.x == 0) {
    __threadfence();
    unsigned gen = atomicAdd(&bar[32], 0u);
    unsigned old = atomicAdd(&bar[0], 1u);
    if (old == gridDim.x - 1) {
      ((volatile unsigned*)bar)[0] = 0;
      __threadfence();
      atomicAdd(&bar[32], 1u);
    } else {
      while (atomicAdd(&bar[32], 0u) == gen) __builtin_amdgcn_s_sleep(1);
    }
    __threadfence();
  }
  __syncthreads();
}

// ---------------- phase: pack adj + W transpose/split + encoder ----------------
__device__ void phase_prep(const GParams& P) {
  const int t = threadIdx.x, b = blockIdx.x;
  {  // pack adjacency: 4096 waves x 16 words
    int gwave = b * 8 + (t >> 6), lane = t & 63;
#pragma unroll
    for (int i = 0; i < 16; i++) {
      int word = gwave * 16 + i;
      unsigned long long m = __ballot(P.adj[(size_t)word * 64 + lane] != 0);
      if (lane == 0) P.mask[word] = m;
    }
  }
  {  // W0/W1 transpose + hi/lo split
    int gtid = b * 512 + t;
    if (gtid < 16384) {
      int head = gtid >> 12, idx = gtid & 4095;
      int o = idx >> 6, k = idx & 63;
      float v = P.gatW0[(head * 64 + k) * 64 + o];
      unsigned short hb = bf16_rne(v);
      P.wt0hi[gtid] = hb;
      P.wt0lo[gtid] = bf16_rne(v - __uint_as_float((unsigned)hb << 16));
    }
    if (gtid < 65536) {
      int head = gtid >> 14, idx = gtid & 16383;
      int o = idx >> 8, k = idx & 255;
      float v = P.gatW1[((size_t)head * 256 + k) * 64 + o];
      unsigned short hb = bf16_rne(v);
      size_t oi = ((size_t)head * 64 + o) * 256 + k;
      P.wt1hi[oi] = hb;
      P.wt1lo[oi] = bf16_rne(v - __uint_as_float((unsigned)hb << 16));
    }
  }
  if (b < 256) {  // encoder MLP, 8 nodes/block (two 4-node halves)
    __shared__ float nfs[2][4][10], x1e[2][4][64], pred[2][4][4][64];
    const int half = t >> 8, tl = t & 255;
    const int j = tl >> 6, o = tl & 63;
    const int n0 = b * 8 + half * 4;
    if (tl < 40) nfs[half][tl / 10][tl % 10] = P.nf[n0 * 10 + tl];
    __syncthreads();
    float acc = P.encb1[o];
#pragma unroll
    for (int k = 0; k < 10; k++) acc = fmaf(nfs[half][j][k], P.encW1[k * 64 + o], acc);
    x1e[half][j][o] = fmaxf(acc, 0.f);
    __syncthreads();
    {
      const int kq = j;
      float pp0 = 0, pp1 = 0, pp2 = 0, pp3 = 0;
#pragma unroll
      for (int kk = 0; kk < 16; kk++) {
        int k = kq * 16 + kk;
        float wv = P.encW2[k * 64 + o];
        pp0 = fmaf(x1e[half][0][k], wv, pp0);
        pp1 = fmaf(x1e[half][1][k], wv, pp1);
        pp2 = fmaf(x1e[half][2][k], wv, pp2);
        pp3 = fmaf(x1e[half][3][k], wv, pp3);
      }
      pred[half][kq][0][o] = pp0; pred[half][kq][1][o] = pp1;
      pred[half][kq][2][o] = pp2; pred[half][kq][3][o] = pp3;
    }
    __syncthreads();
    float v = P.encb2[o] + pred[half][0][j][o] + pred[half][1][j][o] +
              pred[half][2][j][o] + pred[half][3][j][o];
    unsigned short hb = bf16_rne(v);
    P.x0hi[(n0 + j) * 64 + o] = hb;
    P.x0lo[(n0 + j) * 64 + o] = bf16_rne(v - __uint_as_float((unsigned)hb << 16));
  }
}

// ---------------- phase: MFMA projection (blocks 0..255, 2 units/block) ----------------
template <int K>
__device__ void phase_proj(const GParams& P, const unsigned short* xhi, const unsigned short* xlo,
                           const unsigned short* wthi, const unsigned short* wtlo,
                           const float* avec) {
  __shared__ float s1p[2][4][16], s2p[2][4][16];
  const int b = blockIdx.x;
  if (b < 256) {
    const int wave = threadIdx.x >> 6, lane = threadIdx.x & 63;
    const int sub = wave >> 2, wl = wave & 3;
    const int unit = b * 2 + sub;
    const int head = unit & 3, ntile = unit >> 2;
    const int n0 = ntile * 16;
    const int il = lane & 15, kgrp = lane >> 4;
    const int o0 = wl * 16;
    const unsigned short* __restrict__ Ah = wthi + ((size_t)head * 64 + o0 + il) * K;
    const unsigned short* __restrict__ Al = wtlo + ((size_t)head * 64 + o0 + il) * K;
    const unsigned short* __restrict__ Bh = xhi + (size_t)(n0 + il) * K;
    const unsigned short* __restrict__ Bl = xlo + (size_t)(n0 + il) * K;
    f32x4 acc = {0, 0, 0, 0};
#pragma unroll
    for (int ks = 0; ks < K / 32; ks++) {
      const int ka = ks * 32 + kgrp * 8;
      short8v ah = *(const short8v*)(Ah + ka);
      short8v al = *(const short8v*)(Al + ka);
      short8v bh = *(const short8v*)(Bh + ka);
      short8v bl = *(const short8v*)(Bl + ka);
      acc = __builtin_amdgcn_mfma_f32_16x16x32_bf16(ah, bh, acc, 0, 0, 0);
      acc = __builtin_amdgcn_mfma_f32_16x16x32_bf16(al, bh, acc, 0, 0, 0);
      acc = __builtin_amdgcn_mfma_f32_16x16x32_bf16(ah, bl, acc, 0, 0, 0);
    }
    const int n = n0 + il;
    float p1 = 0.f, p2 = 0.f;
#pragma unroll
    for (int r = 0; r < 4; r++) {
      const int o = o0 + kgrp * 4 + r;
      P.hT[((size_t)head * 64 + o) * N + n] = bf16_rne(acc[r]);
      p1 = fmaf(acc[r], avec[head * 128 + o], p1);
      p2 = fmaf(acc[r], avec[head * 128 + 64 + o], p2);
    }
    p1 += __shfl_xor(p1, 16); p1 += __shfl_xor(p1, 32);
    p2 += __shfl_xor(p2, 16); p2 += __shfl_xor(p2, 32);
    if (kgrp == 0) { s1p[sub][wl][il] = p1; s2p[sub][wl][il] = p2; }
    __syncthreads();
    if (threadIdx.x < 32) {
      int sub2 = threadIdx.x >> 4, il2 = threadIdx.x & 15;
      int unit2 = b * 2 + sub2, head2 = unit2 & 3, ntile2 = unit2 >> 2;
      int nn = ntile2 * 16 + il2;
      float v1 = s1p[sub2][0][il2] + s1p[sub2][1][il2] + s1p[sub2][2][il2] + s1p[sub2][3][il2];
      float v2 = s2p[sub2][0][il2] + s2p[sub2][1][il2] + s2p[sub2][2][il2] + s2p[sub2][3][il2];
      P.s1[head2 * N + nn] = v1;
      P.s2[head2 * N + nn] = v2;
      float m1 = v1;
#pragma unroll
      for (int s = 1; s < 16; s <<= 1) m1 = fmaxf(m1, __shfl_xor(m1, s));
      if (il2 == 0) P.pm1[head2 * 128 + ntile2] = m1;
    }
  }
}

// ---------------- phase: fused MFMA aggregation (all 512 blocks) ----------------
__device__ void phase_agg(const GParams& P, float* xoutf,
                          unsigned short* xohi, unsigned short* xolo) {
  __shared__ float red[8][16][65];
  __shared__ float wred[8][16];
  const int b = blockIdx.x;
  const int head = b & 3, p0 = (b >> 2) * 16;
  const int wave = threadIdx.x >> 6, lane = threadIdx.x & 63;
  const int col = lane & 15, kgrp = lane >> 4;
  const int p = p0 + col;
  const float s2pv = P.s2[head * N + p];
  float sm = fmaxf(P.pm1[head * 128 + lane], P.pm1[head * 128 + 64 + lane]);
#pragma unroll
  for (int s = 1; s < 64; s <<= 1) sm = fmaxf(sm, __shfl_xor(sm, s));
  const float mraw = sm + s2pv;
  const float mp = fmaxf(mraw, ALPHA * mraw);
  const float* __restrict__ s1h = P.s1 + head * N;
  const int qbase = wave * 256;
  const unsigned long long* __restrict__ mr = P.mask + (size_t)p * NW + (qbase >> 6);
  unsigned long long mw0 = mr[0], mw1 = mr[1], mw2 = mr[2], mw3 = mr[3];
  const unsigned short* __restrict__ hTu = P.hT;
  size_t boff[4];
#pragma unroll
  for (int ff = 0; ff < 4; ff++) boff[ff] = ((size_t)head * 64 + ff * 16 + col) * N;

  f32x4 acc[4] = {{0,0,0,0},{0,0,0,0},{0,0,0,0},{0,0,0,0}};
  float wsum = 0.f;
#pragma unroll
  for (int ks = 0; ks < 8; ks++) {
    const int qa = qbase + ks * 32 + kgrp * 8;
    float4 s1v0 = *(const float4*)(s1h + qa);
    float4 s1v1 = *(const float4*)(s1h + qa + 4);
    unsigned long long mwsel = (ks < 2) ? mw0 : (ks < 4) ? mw1 : (ks < 6) ? mw2 : mw3;
    unsigned b8 = (unsigned)((mwsel >> ((ks & 1) * 32 + kgrp * 8)) & 0xFFull);
    float sv[8] = {s1v0.x, s1v0.y, s1v0.z, s1v0.w, s1v1.x, s1v1.y, s1v1.z, s1v1.w};
    short8v a_hi, a_lo;
#pragma unroll
    for (int e = 0; e < 8; e++) {
      float ev = sv[e] + s2pv;
      float lr = fmaxf(ev, ALPHA * ev);
      float w = ((b8 >> e) & 1u) ? __expf(lr - mp) : 0.f;
      wsum += w;
      unsigned short hb = bf16_rne(w);
      float hf = __uint_as_float((unsigned)hb << 16);
      a_hi[e] = (short)hb;
      a_lo[e] = (short)bf16_rne(w - hf);
    }
#pragma unroll
    for (int ff = 0; ff < 4; ff++) {
      short8v b_hi = *(const short8v*)(hTu + boff[ff] + qa);
      acc[ff] = __builtin_amdgcn_mfma_f32_16x16x32_bf16(a_hi, b_hi, acc[ff], 0, 0, 0);
      acc[ff] = __builtin_amdgcn_mfma_f32_16x16x32_bf16(a_lo, b_hi, acc[ff], 0, 0, 0);
    }
  }
  wsum += __shfl_xor(wsum, 16);
  wsum += __shfl_xor(wsum, 32);
#pragma unroll
  for (int ff = 0; ff < 4; ff++)
#pragma unroll
    for (int r = 0; r < 4; r++)
      red[wave][kgrp * 4 + r][ff * 16 + col] = acc[ff][r];
  if (lane < 16) wred[wave][lane] = wsum;
  __syncthreads();
#pragma unroll
  for (int rep = 0; rep < 2; rep++) {
    int idx = threadIdx.x + rep * 512;
    int pl = idx >> 6, f = idx & 63;
    float num = 0.f, dn = 0.f;
#pragma unroll
    for (int w = 0; w < 8; w++) { num += red[w][pl][f]; dn += wred[w][pl]; }
    float v = num / dn;
    v = v > 0.f ? v : (__expf(v) - 1.f);
    size_t oi = (size_t)(p0 + pl) * 256 + head * 64 + f;
    if (xoutf) xoutf[oi] = v;
    if (xohi) {
      unsigned short hb = bf16_rne(v);
      float hf = __uint_as_float((unsigned)hb << 16);
      xohi[oi] = hb;
      xolo[oi] = bf16_rne(v - hf);
    }
  }
  __syncthreads();
}

// ---------------- phase: layer-2 projection (blocks 0..255, 8 nodes/block) ----------------
__device__ void phase_h3(const GParams& P) {
  __shared__ float xr[8][256];
  const int b = blockIdx.x, t = threadIdx.x;
  if (b < 256) {
    const int n0 = b * 8;
#pragma unroll
    for (int i = 0; i < 4; i++) {
      int idx = t + i * 512;
      xr[idx >> 8][idx & 255] = P.xB[(size_t)n0 * 256 + idx];
    }
    __syncthreads();
    const int half = t >> 8, tl = t & 255;
    const int head = tl >> 6, o = tl & 63;
    const float* __restrict__ Wh = P.gatW2 + (size_t)head * 256 * 3;
    const float* __restrict__ av = P.gata2 + head * 6;
    float m1 = -3.4e38f;
#pragma unroll
    for (int jj = 0; jj < 4; jj++) {
      float a0 = 0.f, a1 = 0.f, a2 = 0.f;
#pragma unroll
      for (int i = 0; i < 4; i++) {
        int k = o + 64 * i;
        float xv = xr[half * 4 + jj][k];
        a0 = fmaf(xv, Wh[k * 3 + 0], a0);
        a1 = fmaf(xv, Wh[k * 3 + 1], a1);
        a2 = fmaf(xv, Wh[k * 3 + 2], a2);
      }
      for (int s = 32; s; s >>= 1) {
        a0 += __shfl_xor(a0, s); a1 += __shfl_xor(a1, s); a2 += __shfl_xor(a2, s);
      }
      float p1 = a0 * av[0] + a1 * av[1] + a2 * av[2];
      float p2 = a0 * av[3] + a1 * av[4] + a2 * av[5];
      m1 = fmaxf(m1, p1);
      if (o == 0) {
        int nn = n0 + half * 4 + jj;
        float* hq = P.h2 + ((size_t)head * N + nn) * 3;
        hq[0] = a0; hq[1] = a1; hq[2] = a2;
        P.s1[head * N + nn] = p1;
        P.s2[head * N + nn] = p2;
      }
    }
    if (o == 0) P.pm1h3[head * 512 + b * 2 + half] = m1;
  }
}

// ---------------- phase: layer-2 aggregation + head-mean + ELU -> emb ----------------
__device__ void phase_agg2(const GParams& P) {
  __shared__ float red2[2][4][4];
  const int b = blockIdx.x, t = threadIdx.x;
  const int sub = t >> 8, tl = t & 255;
  const int head = tl >> 6, lane = tl & 63;
#pragma unroll
  for (int pass = 0; pass < 2; pass++) {
    const int p = b * 4 + pass * 2 + sub;
    const float s2pv = P.s2[head * N + p];
    float sm = -3.4e38f;
#pragma unroll
    for (int i = 0; i < 8; i++) sm = fmaxf(sm, P.pm1h3[head * 512 + lane + i * 64]);
#pragma unroll
    for (int s = 1; s < 64; s <<= 1) sm = fmaxf(sm, __shfl_xor(sm, s));
    float mraw = sm + s2pv;
    const float mhv = fmaxf(mraw, ALPHA * mraw);
    const float* __restrict__ s1h = P.s1 + head * N;
    float a0 = 0.f, a1 = 0.f, a2 = 0.f, wsum = 0.f;
#pragma unroll 2
    for (int i = 0; i < 32; i++) {
      unsigned long long mwd = P.mask[(size_t)p * NW + i];
      int q = i * 64 + lane;
      if ((mwd >> lane) & 1ull) {
        float e = s1h[q] + s2pv;
        e = fmaxf(e, ALPHA * e);
        float w = __expf(e - mhv);
        const float* __restrict__ hq = P.h2 + ((size_t)head * N + q) * 3;
        a0 = fmaf(w, hq[0], a0);
        a1 = fmaf(w, hq[1], a1);
        a2 = fmaf(w, hq[2], a2);
        wsum += w;
      }
    }
    for (int s = 32; s; s >>= 1) {
      a0 += __shfl_xor(a0, s); a1 += __shfl_xor(a1, s);
      a2 += __shfl_xor(a2, s); wsum += __shfl_xor(wsum, s);
    }
    if (lane == 0) { red2[sub][head][0] = a0; red2[sub][head][1] = a1;
                     red2[sub][head][2] = a2; red2[sub][head][3] = wsum; }
    __syncthreads();
    if (tl < 3) {
      float v = 0.f;
#pragma unroll
      for (int hh = 0; hh < 4; hh++) v += red2[sub][hh][tl] / red2[sub][hh][3];
      v *= 0.25f;
      v = v > 0.f ? v : (__expf(v) - 1.f);
      P.emb[p * 3 + tl] = v;
    }
    __syncthreads();
  }
}

// ---------------- single fused pipeline kernel ----------------
__global__ void __launch_bounds__(512, 4) mega_kernel(GParams P) {
  phase_prep(P);
  gsync(P.bar);
  phase_proj<64>(P, P.x0hi, P.x0lo, P.wt0hi, P.wt0lo, P.gata0);
  gsync(P.bar);
  phase_agg(P, nullptr, P.xAhi, P.xAlo);
  gsync(P.bar);
  phase_proj<256>(P, P.xAhi, P.xAlo, P.wt1hi, P.wt1lo, P.gata1);
  gsync(P.bar);
  phase_agg(P, P.xB, nullptr, nullptr);
  gsync(P.bar);
  phase_h3(P);
  gsync(P.bar);
  phase_agg2(P);
}

// ---------------- all-pairs edge classifier ----------------
__global__ void cls_kernel(const float* __restrict__ emb,
                           const float* __restrict__ W1, const float* __restrict__ b1,
                           const float* __restrict__ W2, const float* __restrict__ b2,
                           float* __restrict__ out) {
  int q = blockIdx.x * 256 + threadIdx.x;
  int p0 = blockIdx.y * 8;
  __shared__ float ep[8][3];
  __shared__ float w1s[96], b1s[32], w2s[32];
  __shared__ float b2s;
  int t = threadIdx.x;
  if (t < 96) w1s[t] = W1[t];
  else if (t < 128) b1s[t - 96] = b1[t - 96];
  else if (t < 160) w2s[t - 128] = W2[t - 128];
  else if (t == 160) b2s = b2[0];
  else if (t >= 192 && t < 216) ((float*)ep)[t - 192] = emb[p0 * 3 + t - 192];
  __syncthreads();
  float e0 = emb[q * 3 + 0], e1 = emb[q * 3 + 1], e2 = emb[q * 3 + 2];
  float d[8][3];
#pragma unroll
  for (int i = 0; i < 8; i++) {
    d[i][0] = fabsf(ep[i][0] - e0);
    d[i][1] = fabsf(ep[i][1] - e1);
    d[i][2] = fabsf(ep[i][2] - e2);
  }
  float acc[8] = {0, 0, 0, 0, 0, 0, 0, 0};
#pragma unroll
  for (int j = 0; j < 32; j++) {
    float c0 = w1s[j], c1 = w1s[32 + j], c2 = w1s[64 + j], bb = b1s[j], w2 = w2s[j];
#pragma unroll
    for (int i = 0; i < 8; i++) {
      float hv = fmaxf(bb + d[i][0] * c0 + d[i][1] * c1 + d[i][2] * c2, 0.f);
      acc[i] += hv * w2;
    }
  }
#pragma unroll
  for (int i = 0; i < 8; i++) {
    float x = acc[i] + b2s;
    out[(size_t)(p0 + i) * N + q] = 1.f / (1.f + __expf(-x));
  }
}

extern "C" void kernel_launch(void* const* d_in, const int* in_sizes, int n_in,
                              void* d_out, int out_size, void* d_ws, size_t ws_size,
                              hipStream_t stream) {
  float* ws = (float*)d_ws;
  unsigned short* hT   = (unsigned short*)ws;              // 262144 f
  float* s1   = ws + 262144;                               // 8192
  float* s2   = s1 + 8192;                                 // 8192
  float* pm1  = s2 + 8192;                                 // 512
  float* pm1h3= pm1 + 512;                                 // 2048
  unsigned short* x0hi = (unsigned short*)(pm1h3 + 2048);  // 65536 f
  unsigned short* x0lo = x0hi + 131072;                    // 65536 f
  unsigned short* wt0hi= x0lo + 131072;                    // 8192 f
  unsigned short* wt0lo= wt0hi + 16384;                    // 8192 f
  unsigned short* wt1hi= wt0lo + 16384;                    // 32768 f
  unsigned short* wt1lo= wt1hi + 65536;                    // 32768 f
  unsigned short* xAhi = wt1lo + 65536;                    // 262144 f
  unsigned short* xAlo = xAhi + 524288;                    // 262144 f
  float* xB   = (float*)(xAlo + 524288);                   // 524288 f
  float* h2   = xB + 524288;                               // 24576 f
  unsigned long long* mask = (unsigned long long*)(h2 + 24576); // 131072 f
  unsigned* bar = (unsigned*)(mask + 65536);               // 64 uints

  float* emb = (float*)d_out;
  float* eprob = emb + N * 3;

  hipMemsetAsync(bar, 0, 256, stream);

  GParams P;
  P.nf = (const float*)d_in[0];   P.adj = (const int*)d_in[1];
  P.encW1 = (const float*)d_in[2]; P.encb1 = (const float*)d_in[3];
  P.encW2 = (const float*)d_in[4]; P.encb2 = (const float*)d_in[5];
  P.gatW0 = (const float*)d_in[6]; P.gata0 = (const float*)d_in[7];
  P.gatW1 = (const float*)d_in[8]; P.gata1 = (const float*)d_in[9];
  P.gatW2 = (const float*)d_in[10]; P.gata2 = (const float*)d_in[11];
  P.mask = mask;
  P.wt0hi = wt0hi; P.wt0lo = wt0lo; P.wt1hi = wt1hi; P.wt1lo = wt1lo;
  P.x0hi = x0hi; P.x0lo = x0lo;
  P.hT = hT; P.s1 = s1; P.s2 = s2; P.pm1 = pm1; P.pm1h3 = pm1h3;
  P.xAhi = xAhi; P.xAlo = xAlo; P.xB = xB; P.h2 = h2; P.emb = emb;
  P.bar = bar;

  mega_kernel<<<dim3(512), dim3(512), 0, stream>>>(P);
  cls_kernel<<<dim3(8, N / 8), dim3(256), 0, stream>>>(
      emb, (const float*)d_in[12], (const float*)d_in[13],
      (const float*)d_in[14], (const float*)d_in[15], eprob);
}